// Round 10
// baseline (414.468 us; speedup 1.0000x reference)
//
#include <hip/hip_runtime.h>
#include <math.h>

// ---------------------------------------------------------------------------
// R10: conv_up_k split by output-column parity -> 2 blocks/CU.
// Block (512 thr) = one (j, ph, pcol): 2 output rows x 128 cols(one parity)
// x 64 co'. Waves: rr(2) x ch(2) x mh(2); wave = 16val+16gate co x 64 q.
// LDS: input dbuf 2x24.96KB + weights 16.4KB single-buffered = 66.3KB.
// Pipeline: stage_in(cc+1) -> compute(cc) -> B1 -> stage_w(cc+1) -> B2.
// Everything else identical to R9.
// ws: [0]mbits | [1KB]sT | [4MB)zeros(3MB span) | [8MB)hcA | [40MB)wt
// ---------------------------------------------------------------------------

#define B_N 8
#define NGF 64
#define HC 128
#define WC 128
#define QN (HC*WC)        // 16384
#define NEF 256
#define SN 32
#define TEMP_INV (1.0f/0.7f)
#define BN_SC 0.99999500003749969f   // 1/sqrt(1+1e-5)
#define TOPK 24

typedef _Float16 f16;
typedef __attribute__((ext_vector_type(8))) _Float16 f16x8;
typedef __attribute__((ext_vector_type(4))) _Float16 f16x4;
typedef __attribute__((ext_vector_type(4))) float f32x4;

__device__ __forceinline__ void gload16(const void* g, void* l) {
    __builtin_amdgcn_global_load_lds(
        (const __attribute__((address_space(1))) void*)g,
        (__attribute__((address_space(3))) void*)l,
        16, 0, 0);
}

// ---------------- mask prep + zero stripes at +{0..3}MB ---------------------
__global__ void prep_mask_k(const void* __restrict__ mraw,
                            unsigned* __restrict__ mbits,
                            unsigned* __restrict__ zp) {
    __shared__ int mode;
    if (threadIdx.x == 0) {
        const unsigned* u = (const unsigned*)mraw;
        bool i32 = true, f32m = true;
        for (int i = 0; i < 64; ++i) {
            unsigned v = u[i];
            if (v > 1u) i32 = false;
            if (v != 0u && v != 0x3F800000u) f32m = false;
        }
        mode = i32 ? 0 : (f32m ? 1 : 2);
    }
    __syncthreads();
    int t = threadIdx.x;
    if (t < 64) zp[(t >> 4) * 262144 + (t & 15)] = 0u;   // 64B at each MB
    if (t < B_N) {
        unsigned bits = 0;
        for (int s = 0; s < SN; ++s) {
            int idx = t * SN + s;
            bool on;
            if (mode == 0)      on = ((const int*)mraw)[idx] != 0;
            else if (mode == 1) on = ((const float*)mraw)[idx] != 0.0f;
            else                on = ((const unsigned char*)mraw)[idx] != 0;
            if (on) bits |= (1u << s);
        }
        mbits[t] = bits;
    }
}

// ---------------- sourceT[b,o,s]: 64 blocks, thread=(o_local,s) -------------
__global__ __launch_bounds__(256) void source_t_k(
        const float* __restrict__ w_ctx, const float* __restrict__ word_embs,
        float* __restrict__ sT) {
    int b = blockIdx.x >> 3;
    int o = ((blockIdx.x & 7) << 3) + (threadIdx.x >> 5);
    int s = threadIdx.x & 31;
    const float* wrow = w_ctx + (size_t)o * NEF;
    const float* wb = word_embs + (size_t)b * NEF * SN + s;
    float acc = 0.0f;
    #pragma unroll 8
    for (int c = 0; c < NEF; ++c) acc += wrow[c] * wb[(size_t)c * SN];
    sT[((size_t)b * NGF + o) * SN + s] = acc;
}

// ---------------- attention: writes h_c granule-major NCHW8c ----------------
__global__ __launch_bounds__(256) void attention_k(
        const float* __restrict__ h_code, const float* __restrict__ sT,
        const unsigned* __restrict__ mbits,
        float* __restrict__ att_out,   // (B,S,Q) fp32
        f16* __restrict__ hc) {        // [b][16][QN][8]: g0..7 h, g8..15 wctx
    int r0 = blockIdx.x * 256;
    int b = r0 >> 14;
    __shared__ float st[NGF * SN];
    const float* stg = sT + (size_t)b * NGF * SN;
    for (int i = threadIdx.x; i < NGF * SN; i += 256) st[i] = stg[i];
    __syncthreads();
    int q = (r0 & (QN - 1)) + threadIdx.x;

    const float* hb = h_code + (size_t)b * NGF * QN + q;
    f16* hcb = hc + (size_t)b * QN * 128;

    float a[SN];
    #pragma unroll
    for (int s = 0; s < SN; ++s) a[s] = 0.0f;
    for (int g8 = 0; g8 < 8; ++g8) {
        f16x8 t;
        #pragma unroll
        for (int r = 0; r < 8; ++r) {
            float v = hb[(size_t)(g8 * 8 + r) * QN];
            t[r] = (f16)v;
            #pragma unroll
            for (int s = 0; s < SN; ++s) a[s] += v * st[(g8 * 8 + r) * SN + s];
        }
        *(f16x8*)(hcb + ((size_t)g8 * QN + q) * 8) = t;   // contiguous 16B/lane
    }
    unsigned mb = mbits[q & 7];       // reference tile quirk: mask row = q%8
    #pragma unroll
    for (int s = 0; s < SN; ++s)
        a[s] = ((mb >> s) & 1u) ? -INFINITY : a[s] * TEMP_INV;

    // top-k threshold via stable rank (24th largest incl. duplicates).
    float thr = -INFINITY;
    #pragma unroll
    for (int s = 0; s < SN; ++s) {
        int rank = 0;
        #pragma unroll
        for (int j = 0; j < SN; ++j)
            rank += (a[j] > a[s]) || (a[j] == a[s] && j < s);
        if (rank == TOPK - 1) thr = a[s];
    }
    float m = -INFINITY;
    #pragma unroll
    for (int s = 0; s < SN; ++s) {
        if (a[s] < thr) a[s] = -INFINITY;
        m = fmaxf(m, a[s]);
    }
    float p[SN];
    if (m == -INFINITY) {
        #pragma unroll
        for (int s = 0; s < SN; ++s) p[s] = 1.0f / SN;
    } else {
        float sum = 0.0f;
        #pragma unroll
        for (int s = 0; s < SN; ++s) { p[s] = __expf(a[s] - m); sum += p[s]; }
        float inv = 1.0f / sum;
        #pragma unroll
        for (int s = 0; s < SN; ++s) p[s] *= inv;
    }
    float* ao = att_out + (size_t)b * SN * QN + q;
    #pragma unroll
    for (int s = 0; s < SN; ++s) ao[(size_t)s * QN] = p[s];
    for (int g8 = 0; g8 < 8; ++g8) {
        f16x8 t;
        #pragma unroll
        for (int r = 0; r < 8; ++r) {
            float acc = 0.0f;
            #pragma unroll
            for (int s = 0; s < SN; ++s) acc += st[(g8 * 8 + r) * SN + s] * p[s];
            t[r] = (f16)acc;
        }
        *(f16x8*)(hcb + ((size_t)(8 + g8) * QN + q) * 8) = t;
    }
}

// ---------------- weight transform: OIHW fp32 -> [cb][cc][t][co'][g'][8] f16 -
__global__ __launch_bounds__(256) void wt_transform_k(
        const float* __restrict__ w, f16* __restrict__ wt,
        int total, int HALF /*0 = non-GLU*/) {
    int idx = blockIdx.x * 256 + threadIdx.x;
    if (idx >= total) return;
    int e   = idx & 7;
    int gp  = (idx >> 3) & 3;
    int cop = (idx >> 5) & 63;
    int u   = idx >> 11;
    int t   = u % 9;
    int v   = u / 9;
    int cc  = v & 3;
    int cb  = v >> 2;
    int g   = gp ^ ((cop >> 1) & 3);
    int ci  = cc * 32 + g * 8 + e;
    int co  = HALF ? (cop < 32 ? cb * 32 + cop : HALF + cb * 32 + (cop - 32))
                   : cb * 64 + cop;
    wt[idx] = (f16)w[((size_t)co * 128 + ci) * 9 + t];
}

// ---------------- UP weight transform: parity-collapsed 2x2 kernels --------
__global__ __launch_bounds__(256) void wt_up_transform_k(
        const float* __restrict__ w, f16* __restrict__ wt) {
    int idx = blockIdx.x * 256 + threadIdx.x;    // total 524288
    int e   = idx & 7;
    int gp  = (idx >> 3) & 3;
    int cop = (idx >> 5) & 63;
    int tap = (idx >> 11) & 3;
    int pw  = (idx >> 13) & 1;
    int cc  = (idx >> 14) & 3;
    int ph  = (idx >> 16) & 1;
    int cb  = (idx >> 17) & 1;
    int g   = gp ^ ((cop >> 1) & 3);
    int ci  = cc * 32 + g * 8 + e;
    int co  = cop < 32 ? cb * 32 + cop : 64 + cb * 32 + (cop - 32);
    int ra = tap >> 1, bb = tap & 1;
    const float* wp = w + ((size_t)co * 128 + ci) * 9;
    float acc = 0.0f;
    #pragma unroll
    for (int kh = 0; kh < 3; ++kh) {
        int rma = (ph == 0) ? (kh == 0 ? 0 : 1) : (kh == 2 ? 1 : 0);
        if (rma != ra) continue;
        #pragma unroll
        for (int kw = 0; kw < 3; ++kw) {
            int cma = (pw == 0) ? (kw == 0 ? 0 : 1) : (kw == 2 ? 1 : 0);
            if (cma == bb) acc += wp[kh * 3 + kw];
        }
    }
    wt[idx] = (f16)acc;
}

// ---------------- non-UP implicit-GEMM conv3x3 via MFMA ---------------------
template<int COUT, bool GLU, bool RES, int HOUT, int WOUT>
__global__ __launch_bounds__(256) void conv_mfma_k(
        const f16* __restrict__ in, const f16* __restrict__ wt,
        const float* __restrict__ gamma, const float* __restrict__ beta,
        const f16* __restrict__ res, f16* __restrict__ outh,
        const char* __restrict__ zeros) {
    constexpr int HALF = COUT / 2;
    constexpr int OCH  = GLU ? HALF : COUT;
    constexpr int HIN  = HOUT;
    constexpr int WIN  = WOUT;
    constexpr int RPT  = 256 / WOUT;
    constexpr int ROWS_IN = RPT + 2;
    constexpr int NIN_G   = ROWS_IN * 520;
    constexpr int NIN_IT  = (NIN_G + 255) / 256;
    constexpr int NIN_PAD = NIN_IT * 256;
    constexpr int WBYTES  = 36864;
    constexpr int WIT     = 9;

    __shared__ char smem[NIN_PAD * 16 + WBYTES];
    char* sW = smem + NIN_PAD * 16;

    const int tid = threadIdx.x, lane = tid & 63, wv = tid >> 6;
    const int l15 = lane & 15, kg = lane >> 4;
    const int b = blockIdx.z, cb = blockIdx.y, qt = blockIdx.x;
    const int q0 = qt * 256;
    const int h0 = q0 / WOUT;

    f32x4 acc[4][4];
    #pragma unroll
    for (int m = 0; m < 4; ++m)
        #pragma unroll
        for (int n = 0; n < 4; ++n) acc[m][n] = (f32x4){0.f, 0.f, 0.f, 0.f};

    const f16* inb = in + (size_t)b * HIN * WIN * 128;
    const char* wtb = (const char*)wt + (size_t)cb * 147456;

    const char* srcK[NIN_IT];
    #pragma unroll
    for (int k = 0; k < NIN_IT; ++k) {
        int idx = (k << 8) + tid;
        int r = idx / 520;
        int rem = idx - r * 520;
        int wi = rem >> 2, gp = rem & 3;
        int g = gp ^ ((wi >> 1) & 3);
        int gh = h0 - 1 + r;
        int gw = wi - 1;
        const char* s = zeros;
        if (r < ROWS_IN && (unsigned)gh < (unsigned)HOUT && (unsigned)gw < (unsigned)WOUT)
            s = (const char*)(inb + (((size_t)g * (HIN * WIN) + (size_t)gh * WIN + gw) << 3));
        srcK[k] = s;
    }
    const int dstB = (tid & 192) << 4;

    for (int cc = 0; cc < 4; ++cc) {
        #pragma unroll
        for (int k = 0; k < NIN_IT; ++k)
            gload16(srcK[k] + (cc << 20), smem + (k << 12) + dstB);
        const char* wsrc = wtb + cc * WBYTES + (tid << 4);
        #pragma unroll
        for (int k = 0; k < WIT; ++k)
            gload16(wsrc + (k << 12), sW + (k << 12) + dstB);
        __syncthreads();

        #pragma unroll
        for (int t = 0; t < 9; ++t) {
            f16x8 af[4], bf[4];
            #pragma unroll
            for (int m = 0; m < 4; ++m) {
                int co = m * 16 + l15;
                af[m] = *(const f16x8*)(sW + (t << 12) + (co << 6)
                                        + ((kg ^ ((co >> 1) & 3)) << 4));
            }
            #pragma unroll
            for (int n = 0; n < 4; ++n) {
                const int kh = t / 3, kw = t % 3;
                int row = (wv >> 1) + kh;
                int wi = ((wv & 1) << 6) + (n << 4) + l15 + kw;
                int off = row * 8320 + wi * 64 + ((kg ^ ((wi >> 1) & 3)) << 4);
                bf[n] = *(const f16x8*)(smem + off);
            }
            #pragma unroll
            for (int m = 0; m < 4; ++m)
                #pragma unroll
                for (int n = 0; n < 4; ++n)
                    acc[m][n] = __builtin_amdgcn_mfma_f32_16x16x32_f16(af[m], bf[n], acc[m][n], 0, 0, 0);
        }
        __syncthreads();
    }

    const int r4 = kg * 4;
    if (GLU) {
        #pragma unroll
        for (int mv = 0; mv < 2; ++mv) {
            const int v0 = cb * 32 + mv * 16 + r4;
            float s1[4], o1[4], s2[4], o2[4];
            #pragma unroll
            for (int r = 0; r < 4; ++r) {
                s1[r] = gamma[v0 + r] * BN_SC;        o1[r] = beta[v0 + r];
                s2[r] = gamma[v0 + r + HALF] * BN_SC; o2[r] = beta[v0 + r + HALF];
            }
            #pragma unroll
            for (int n = 0; n < 4; ++n) {
                float ov[4];
                #pragma unroll
                for (int r = 0; r < 4; ++r) {
                    float yv = acc[mv][n][r] * s1[r] + o1[r];
                    float zv = acc[mv + 2][n][r] * s2[r] + o2[r];
                    ov[r] = yv / (1.0f + __expf(-zv));
                }
                const int qc = (wv << 6) + (n << 4) + l15;
                f16x4 tv;
                #pragma unroll
                for (int r = 0; r < 4; ++r) tv[r] = (f16)ov[r];
                *(f16x4*)(outh + ((((size_t)b * (OCH / 8) + (v0 >> 3)) << 14)
                                  + q0 + qc) * 8 + (v0 & 7)) = tv;
            }
        }
    } else {
        #pragma unroll
        for (int m = 0; m < 4; ++m) {
            const int c0 = cb * 64 + m * 16 + r4;
            float s[4], o[4];
            #pragma unroll
            for (int r = 0; r < 4; ++r) {
                s[r] = gamma[c0 + r] * BN_SC; o[r] = beta[c0 + r];
            }
            #pragma unroll
            for (int n = 0; n < 4; ++n) {
                const int qc = (wv << 6) + (n << 4) + l15;
                const size_t gaddr = ((((size_t)b * 16 + (c0 >> 3)) << 14) + q0 + qc) * 8 + (c0 & 7);
                float ov[4];
                #pragma unroll
                for (int r = 0; r < 4; ++r) ov[r] = acc[m][n][r] * s[r] + o[r];
                if (RES) {
                    f16x4 rv = *(const f16x4*)(res + gaddr);
                    #pragma unroll
                    for (int r = 0; r < 4; ++r) ov[r] += (float)rv[r];
                }
                f16x4 tv;
                #pragma unroll
                for (int r = 0; r < 4; ++r) tv[r] = (f16)ov[r];
                *(f16x4*)(outh + gaddr) = tv;
            }
        }
    }
}

// ---------------- UP conv: parity-split, 2 blocks/CU, pipelined -------------
// Block = (j, ph, pcol): 2 output rows x 128 one-parity cols x 64 co'.
// Waves: rr = wv>>2, ch = (wv>>1)&1, mh = wv&1; wave m-tiles {mh, mh+2}
// (16 value + 16 gate channels), 64 q. Input dbuf; weights single-buffered.
__global__ __launch_bounds__(512, 4) void conv_up_k(
        const f16* __restrict__ in, const f16* __restrict__ wt,
        const float* __restrict__ gamma, const float* __restrict__ beta,
        float* __restrict__ outf, const char* __restrict__ zeros) {
    constexpr int HIN = 128, WIN = 128;
    constexpr int INB = 24960;                // input granules per buffer
    __shared__ char smem[2 * INB + 16384];    // 66,304 B -> 2 blocks/CU
    char* wB = smem + 2 * INB;

    const int tid = threadIdx.x, lane = tid & 63, wv = tid >> 6;
    const int l15 = lane & 15, kg = lane >> 4;
    const int b = blockIdx.z, cb = blockIdx.y;
    const int j = blockIdx.x >> 2, ph = (blockIdx.x >> 1) & 1, pcol = blockIdx.x & 1;
    const int rr = wv >> 2;                   // output row within pair
    const int ch = (wv >> 1) & 1;             // source col half
    const int mh = wv & 1;                    // co-half (value m=mh, gate m=mh+2)

    f32x4 acc[2][4];
    #pragma unroll
    for (int m = 0; m < 2; ++m)
        #pragma unroll
        for (int n = 0; n < 4; ++n) acc[m][n] = (f32x4){0.f, 0.f, 0.f, 0.f};

    const f16* inb = in + (size_t)b * HIN * WIN * 128;
    const char* wtb = (const char*)wt + (size_t)(cb * 2 + ph) * 131072
                      + pcol * 16384;

    // hoisted input sources: 3 full iters (512 thr) + 24-granule tail (wave 0)
    const char* srcK[4];
    #pragma unroll
    for (int k = 0; k < 4; ++k) {
        int idx = (k < 3) ? ((k << 9) + tid) : (1536 + tid);
        int r = idx / 520;
        int rem = idx - r * 520;
        int wi = rem >> 2, gp = rem & 3;
        int g = gp ^ ((wi >> 1) & 3);
        int sh = 2 * j - 1 + ph + r;
        int sw = wi - 1;
        const char* s = zeros;
        if (r < 3 && (unsigned)sh < (unsigned)HIN && (unsigned)sw < (unsigned)WIN)
            s = (const char*)(inb + (((size_t)g * (HIN * WIN) + (size_t)sh * WIN + sw) << 3));
        srcK[k] = s;
    }
    const int dstB = (tid & 448) << 4;

    auto stage_in = [&](int cc, int buf) {
        char* base = smem + buf * INB;
        #pragma unroll
        for (int k = 0; k < 3; ++k)
            gload16(srcK[k] + (cc << 20), base + (k << 13) + dstB);
        if (tid < 24)
            gload16(srcK[3] + (cc << 20), base + 24576);
    };
    auto stage_w = [&](int cc) {
        const char* wsrc = wtb + cc * 32768 + (tid << 4);
        #pragma unroll
        for (int k = 0; k < 2; ++k)
            gload16(wsrc + (k << 13), wB + (k << 13) + dstB);
    };

    stage_in(0, 0);
    stage_w(0);
    __syncthreads();
    for (int cc = 0; cc < 4; ++cc) {
        if (cc < 3) stage_in(cc + 1, (cc + 1) & 1);    // prefetch under compute
        const char* bb = smem + (cc & 1) * INB;

        #pragma unroll
        for (int t = 0; t < 4; ++t) {
            f16x8 af[2], bf[4];
            #pragma unroll
            for (int m = 0; m < 2; ++m) {
                int co = (mh + m * 2) * 16 + l15;
                af[m] = *(const f16x8*)(wB + (t << 12) + (co << 6)
                                        + ((kg ^ ((co >> 1) & 3)) << 4));
            }
            #pragma unroll
            for (int n = 0; n < 4; ++n) {
                int si = ch * 64 + (n << 4) + l15 + (t & 1) + pcol;  // halo'd
                int off = (rr + (t >> 1)) * 8320 + si * 64
                          + ((kg ^ ((si >> 1) & 3)) << 4);
                bf[n] = *(const f16x8*)(bb + off);
            }
            #pragma unroll
            for (int m = 0; m < 2; ++m)
                #pragma unroll
                for (int n = 0; n < 4; ++n)
                    acc[m][n] = __builtin_amdgcn_mfma_f32_16x16x32_f16(af[m], bf[n], acc[m][n], 0, 0, 0);
        }
        __syncthreads();                       // drains input prefetch (hidden)
        if (cc < 3) {
            stage_w(cc + 1);                   // refill weight buffer
            __syncthreads();                   // 16KB L2-hot drain
        }
    }

    // epilogue: BN + GLU -> fp32 NCHW
    const int v0 = cb * 32 + mh * 16 + kg * 4;     // value channel base
    const int h = 4 * j + 2 * rr + ph;
    float s1[4], o1[4], s2[4], o2[4];
    #pragma unroll
    for (int r = 0; r < 4; ++r) {
        s1[r] = gamma[v0 + r] * BN_SC;      o1[r] = beta[v0 + r];
        s2[r] = gamma[v0 + r + 64] * BN_SC; o2[r] = beta[v0 + r + 64];
    }
    #pragma unroll
    for (int n = 0; n < 4; ++n) {
        const int w = 2 * (ch * 64 + (n << 4) + l15) + pcol;
        float ov[4];
        #pragma unroll
        for (int r = 0; r < 4; ++r) {
            float yv = acc[0][n][r] * s1[r] + o1[r];
            float zv = acc[1][n][r] * s2[r] + o2[r];
            ov[r] = yv / (1.0f + __expf(-zv));
        }
        #pragma unroll
        for (int r = 0; r < 4; ++r)
            outf[(((size_t)b * 64 + v0 + r) * 256 + h) * 256 + w] = ov[r];
    }
}

// ---------------------------------------------------------------------------
extern "C" void kernel_launch(void* const* d_in, const int* in_sizes, int n_in,
                              void* d_out, int out_size, void* d_ws, size_t ws_size,
                              hipStream_t stream) {
    (void)in_sizes; (void)n_in; (void)out_size; (void)ws_size;
    const float* h_code    = (const float*)d_in[0];
    const float* word_embs = (const float*)d_in[2];
    const void*  mask      = d_in[3];
    const float* w_ctx     = (const float*)d_in[4];
    const float* r0_w1 = (const float*)d_in[5];
    const float* r0_g1 = (const float*)d_in[6];
    const float* r0_b1 = (const float*)d_in[7];
    const float* r0_w2 = (const float*)d_in[8];
    const float* r0_g2 = (const float*)d_in[9];
    const float* r0_b2 = (const float*)d_in[10];
    const float* r1_w1 = (const float*)d_in[11];
    const float* r1_g1 = (const float*)d_in[12];
    const float* r1_b1 = (const float*)d_in[13];
    const float* r1_w2 = (const float*)d_in[14];
    const float* r1_g2 = (const float*)d_in[15];
    const float* r1_b2 = (const float*)d_in[16];
    const float* up_w  = (const float*)d_in[17];
    const float* up_g  = (const float*)d_in[18];
    const float* up_b  = (const float*)d_in[19];

    float* outp = (float*)d_out;                         // (8,64,256,256) fp32
    float* attp = outp + (size_t)B_N * NGF * 4 * HC * WC;

    unsigned* mbits = (unsigned*)d_ws;
    float* sT  = (float*)((char*)d_ws + 1024);
    char* zeros = (char*)d_ws + ((size_t)4 << 20);                 // 3MB+64B span
    f16* hcA   = (f16*)((char*)d_ws + ((size_t)8 << 20));          // 32MB
    f16* wtbuf = (f16*)((char*)d_ws + ((size_t)40 << 20));         // ~3MB

    const int W1_TOT = 4 * 4 * 9 * 64 * 32;   // 294912 (GLU 256-out)
    const int W2_TOT = 2 * 4 * 9 * 64 * 32;   // 147456
    const int WUP_TOT = 2 * 2 * 4 * 2 * 4 * 64 * 32;   // 524288 (parity 2x2)
    f16* Wr0c1 = wtbuf;
    f16* Wr0c2 = Wr0c1 + W1_TOT;
    f16* Wr1c1 = Wr0c2 + W2_TOT;
    f16* Wr1c2 = Wr1c1 + W1_TOT;
    f16* Wup   = Wr1c2 + W2_TOT;

    f16* Bbuf = (f16*)d_out;                               // [0,32MB)
    f16* Cbuf = (f16*)((char*)d_out + ((size_t)32 << 20)); // [32,64MB)

    prep_mask_k<<<1, 64, 0, stream>>>(mask, mbits, (unsigned*)zeros);
    source_t_k<<<64, 256, 0, stream>>>(w_ctx, word_embs, sT);

    wt_transform_k<<<(W1_TOT + 255) / 256, 256, 0, stream>>>(r0_w1, Wr0c1, W1_TOT, 128);
    wt_transform_k<<<(W2_TOT + 255) / 256, 256, 0, stream>>>(r0_w2, Wr0c2, W2_TOT, 0);
    wt_transform_k<<<(W1_TOT + 255) / 256, 256, 0, stream>>>(r1_w1, Wr1c1, W1_TOT, 128);
    wt_transform_k<<<(W2_TOT + 255) / 256, 256, 0, stream>>>(r1_w2, Wr1c2, W2_TOT, 0);
    wt_up_transform_k<<<WUP_TOT / 256, 256, 0, stream>>>(up_w, Wup);

    attention_k<<<(B_N * QN) / 256, 256, 0, stream>>>(h_code, sT, mbits, attp, hcA);

    // r0: conv1+GLU (hcA->B), conv2+res hcA (B->C)
    conv_mfma_k<256, true,  false, 128, 128>
        <<<dim3(64, 4, B_N), 256, 0, stream>>>(hcA, Wr0c1, r0_g1, r0_b1, nullptr, Bbuf, zeros);
    conv_mfma_k<128, false, true,  128, 128>
        <<<dim3(64, 2, B_N), 256, 0, stream>>>(Bbuf, Wr0c2, r0_g2, r0_b2, hcA, Cbuf, zeros);
    // r1: conv1+GLU (C->B), conv2+res C (B->hcA)
    conv_mfma_k<256, true,  false, 128, 128>
        <<<dim3(64, 4, B_N), 256, 0, stream>>>(Cbuf, Wr1c1, r1_g1, r1_b1, nullptr, Bbuf, zeros);
    conv_mfma_k<128, false, true,  128, 128>
        <<<dim3(64, 2, B_N), 256, 0, stream>>>(Bbuf, Wr1c2, r1_g2, r1_b2, Cbuf, hcA, zeros);
    // upsample2x + conv + GLU -> final fp32 NCHW (parity-split, 2 blocks/CU)
    conv_up_k<<<dim3(256, 2, B_N), 512, 0, stream>>>(hcA, Wup, up_g, up_b, outp, zeros);
}

// Round 11
// 392.986 us; speedup vs baseline: 1.0547x; 1.0547x over previous
//
#include <hip/hip_runtime.h>
#include <math.h>

// ---------------------------------------------------------------------------
// R11: (a) conv_up reverted to R9 (2-phase dbuf, 106us verified; R10 parity
// split doubled FETCH+WRITE). (b) non-UP convs -> 512-thread q-512 tile with
// 2-phase pipeline: input dbuf (stage cc+1 under compute cc), weights
// single-buffered (refill between barriers, L2-hot). LDS 148KB, 1 blk/CU.
// ws: [0]mbits | [1KB]sT | [4MB)zeros(3MB span) | [8MB)hcA | [40MB)wt
// ---------------------------------------------------------------------------

#define B_N 8
#define NGF 64
#define HC 128
#define WC 128
#define QN (HC*WC)        // 16384
#define NEF 256
#define SN 32
#define TEMP_INV (1.0f/0.7f)
#define BN_SC 0.99999500003749969f   // 1/sqrt(1+1e-5)
#define TOPK 24

typedef _Float16 f16;
typedef __attribute__((ext_vector_type(8))) _Float16 f16x8;
typedef __attribute__((ext_vector_type(4))) _Float16 f16x4;
typedef __attribute__((ext_vector_type(4))) float f32x4;

__device__ __forceinline__ void gload16(const void* g, void* l) {
    __builtin_amdgcn_global_load_lds(
        (const __attribute__((address_space(1))) void*)g,
        (__attribute__((address_space(3))) void*)l,
        16, 0, 0);
}

// ---------------- mask prep + zero stripes at +{0..3}MB ---------------------
__global__ void prep_mask_k(const void* __restrict__ mraw,
                            unsigned* __restrict__ mbits,
                            unsigned* __restrict__ zp) {
    __shared__ int mode;
    if (threadIdx.x == 0) {
        const unsigned* u = (const unsigned*)mraw;
        bool i32 = true, f32m = true;
        for (int i = 0; i < 64; ++i) {
            unsigned v = u[i];
            if (v > 1u) i32 = false;
            if (v != 0u && v != 0x3F800000u) f32m = false;
        }
        mode = i32 ? 0 : (f32m ? 1 : 2);
    }
    __syncthreads();
    int t = threadIdx.x;
    if (t < 64) zp[(t >> 4) * 262144 + (t & 15)] = 0u;   // 64B at each MB
    if (t < B_N) {
        unsigned bits = 0;
        for (int s = 0; s < SN; ++s) {
            int idx = t * SN + s;
            bool on;
            if (mode == 0)      on = ((const int*)mraw)[idx] != 0;
            else if (mode == 1) on = ((const float*)mraw)[idx] != 0.0f;
            else                on = ((const unsigned char*)mraw)[idx] != 0;
            if (on) bits |= (1u << s);
        }
        mbits[t] = bits;
    }
}

// ---------------- sourceT[b,o,s]: 64 blocks, thread=(o_local,s) -------------
__global__ __launch_bounds__(256) void source_t_k(
        const float* __restrict__ w_ctx, const float* __restrict__ word_embs,
        float* __restrict__ sT) {
    int b = blockIdx.x >> 3;
    int o = ((blockIdx.x & 7) << 3) + (threadIdx.x >> 5);
    int s = threadIdx.x & 31;
    const float* wrow = w_ctx + (size_t)o * NEF;
    const float* wb = word_embs + (size_t)b * NEF * SN + s;
    float acc = 0.0f;
    #pragma unroll 8
    for (int c = 0; c < NEF; ++c) acc += wrow[c] * wb[(size_t)c * SN];
    sT[((size_t)b * NGF + o) * SN + s] = acc;
}

// ---------------- attention: writes h_c granule-major NCHW8c ----------------
__global__ __launch_bounds__(256) void attention_k(
        const float* __restrict__ h_code, const float* __restrict__ sT,
        const unsigned* __restrict__ mbits,
        float* __restrict__ att_out,   // (B,S,Q) fp32
        f16* __restrict__ hc) {        // [b][16][QN][8]: g0..7 h, g8..15 wctx
    int r0 = blockIdx.x * 256;
    int b = r0 >> 14;
    __shared__ float st[NGF * SN];
    const float* stg = sT + (size_t)b * NGF * SN;
    for (int i = threadIdx.x; i < NGF * SN; i += 256) st[i] = stg[i];
    __syncthreads();
    int q = (r0 & (QN - 1)) + threadIdx.x;

    const float* hb = h_code + (size_t)b * NGF * QN + q;
    f16* hcb = hc + (size_t)b * QN * 128;

    float a[SN];
    #pragma unroll
    for (int s = 0; s < SN; ++s) a[s] = 0.0f;
    for (int g8 = 0; g8 < 8; ++g8) {
        f16x8 t;
        #pragma unroll
        for (int r = 0; r < 8; ++r) {
            float v = hb[(size_t)(g8 * 8 + r) * QN];
            t[r] = (f16)v;
            #pragma unroll
            for (int s = 0; s < SN; ++s) a[s] += v * st[(g8 * 8 + r) * SN + s];
        }
        *(f16x8*)(hcb + ((size_t)g8 * QN + q) * 8) = t;   // contiguous 16B/lane
    }
    unsigned mb = mbits[q & 7];       // reference tile quirk: mask row = q%8
    #pragma unroll
    for (int s = 0; s < SN; ++s)
        a[s] = ((mb >> s) & 1u) ? -INFINITY : a[s] * TEMP_INV;

    // top-k threshold via stable rank (24th largest incl. duplicates).
    float thr = -INFINITY;
    #pragma unroll
    for (int s = 0; s < SN; ++s) {
        int rank = 0;
        #pragma unroll
        for (int j = 0; j < SN; ++j)
            rank += (a[j] > a[s]) || (a[j] == a[s] && j < s);
        if (rank == TOPK - 1) thr = a[s];
    }
    float m = -INFINITY;
    #pragma unroll
    for (int s = 0; s < SN; ++s) {
        if (a[s] < thr) a[s] = -INFINITY;
        m = fmaxf(m, a[s]);
    }
    float p[SN];
    if (m == -INFINITY) {
        #pragma unroll
        for (int s = 0; s < SN; ++s) p[s] = 1.0f / SN;
    } else {
        float sum = 0.0f;
        #pragma unroll
        for (int s = 0; s < SN; ++s) { p[s] = __expf(a[s] - m); sum += p[s]; }
        float inv = 1.0f / sum;
        #pragma unroll
        for (int s = 0; s < SN; ++s) p[s] *= inv;
    }
    float* ao = att_out + (size_t)b * SN * QN + q;
    #pragma unroll
    for (int s = 0; s < SN; ++s) ao[(size_t)s * QN] = p[s];
    for (int g8 = 0; g8 < 8; ++g8) {
        f16x8 t;
        #pragma unroll
        for (int r = 0; r < 8; ++r) {
            float acc = 0.0f;
            #pragma unroll
            for (int s = 0; s < SN; ++s) acc += st[(g8 * 8 + r) * SN + s] * p[s];
            t[r] = (f16)acc;
        }
        *(f16x8*)(hcb + ((size_t)(8 + g8) * QN + q) * 8) = t;
    }
}

// ---------------- weight transform: OIHW fp32 -> [cb][cc][t][co'][g'][8] f16 -
__global__ __launch_bounds__(256) void wt_transform_k(
        const float* __restrict__ w, f16* __restrict__ wt,
        int total, int HALF /*0 = non-GLU*/) {
    int idx = blockIdx.x * 256 + threadIdx.x;
    if (idx >= total) return;
    int e   = idx & 7;
    int gp  = (idx >> 3) & 3;
    int cop = (idx >> 5) & 63;
    int u   = idx >> 11;
    int t   = u % 9;
    int v   = u / 9;
    int cc  = v & 3;
    int cb  = v >> 2;
    int g   = gp ^ ((cop >> 1) & 3);
    int ci  = cc * 32 + g * 8 + e;
    int co  = HALF ? (cop < 32 ? cb * 32 + cop : HALF + cb * 32 + (cop - 32))
                   : cb * 64 + cop;
    wt[idx] = (f16)w[((size_t)co * 128 + ci) * 9 + t];
}

// ---------------- UP weight transform: parity-collapsed 2x2 kernels --------
__global__ __launch_bounds__(256) void wt_up_transform_k(
        const float* __restrict__ w, f16* __restrict__ wt) {
    int idx = blockIdx.x * 256 + threadIdx.x;    // total 524288
    int e   = idx & 7;
    int gp  = (idx >> 3) & 3;
    int cop = (idx >> 5) & 63;
    int tap = (idx >> 11) & 3;
    int pw  = (idx >> 13) & 1;
    int cc  = (idx >> 14) & 3;
    int ph  = (idx >> 16) & 1;
    int cb  = (idx >> 17) & 1;
    int g   = gp ^ ((cop >> 1) & 3);
    int ci  = cc * 32 + g * 8 + e;
    int co  = cop < 32 ? cb * 32 + cop : 64 + cb * 32 + (cop - 32);
    int ra = tap >> 1, bb = tap & 1;
    const float* wp = w + ((size_t)co * 128 + ci) * 9;
    float acc = 0.0f;
    #pragma unroll
    for (int kh = 0; kh < 3; ++kh) {
        int rma = (ph == 0) ? (kh == 0 ? 0 : 1) : (kh == 2 ? 1 : 0);
        if (rma != ra) continue;
        #pragma unroll
        for (int kw = 0; kw < 3; ++kw) {
            int cma = (pw == 0) ? (kw == 0 ? 0 : 1) : (kw == 2 ? 1 : 0);
            if (cma == bb) acc += wp[kh * 3 + kw];
        }
    }
    wt[idx] = (f16)acc;
}

// ---------------- non-UP conv3x3: 512 thr, q-512 tile, 2-phase pipeline -----
// 8 waves = row lr(4) x col-half chf(2); per wave 64co' x 64q, 144 MFMA/cc.
// Input dbuf (stage cc+1 before compute cc); weights single-buf (refill
// between barriers). LDS = 2*57344 + 36864 = 151,552B -> 1 block/CU.
template<int COUT, bool GLU, bool RES>
__global__ __launch_bounds__(512) void conv_mfma_k(
        const f16* __restrict__ in, const f16* __restrict__ wt,
        const float* __restrict__ gamma, const float* __restrict__ beta,
        const f16* __restrict__ res, f16* __restrict__ outh,
        const char* __restrict__ zeros) {
    constexpr int HALF = COUT / 2;
    constexpr int OCH  = GLU ? HALF : COUT;
    constexpr int IBUF = 57344;               // 3584 granules (3120 real + pad)

    __shared__ char smem[2 * IBUF + 36864];
    char* wB = smem + 2 * IBUF;

    const int tid = threadIdx.x, lane = tid & 63, wv = tid >> 6;
    const int l15 = lane & 15, kg = lane >> 4;
    const int b = blockIdx.z, cb = blockIdx.y, qt = blockIdx.x;
    const int q0 = qt * 512;
    const int h0 = qt * 4;
    const int lr = wv >> 1, chf = wv & 1;

    f32x4 acc[4][4];
    #pragma unroll
    for (int m = 0; m < 4; ++m)
        #pragma unroll
        for (int n = 0; n < 4; ++n) acc[m][n] = (f32x4){0.f, 0.f, 0.f, 0.f};

    const f16* inb = in + (size_t)b * QN * 128;
    const char* wtb = (const char*)wt + (size_t)cb * 147456;

    // hoisted input sources (cc-invariant; +cc*1MB plane stride per cc)
    const char* srcK[7];
    #pragma unroll
    for (int k = 0; k < 7; ++k) {
        int idx = (k << 9) + tid;
        int r = idx / 520;
        int rem = idx - r * 520;
        int wi = rem >> 2, gp = rem & 3;
        int g = gp ^ ((wi >> 1) & 3);
        int gh = h0 - 1 + r;
        int gw = wi - 1;
        const char* s = zeros;
        if (r < 6 && (unsigned)gh < (unsigned)HC && (unsigned)gw < (unsigned)WC)
            s = (const char*)(inb + (((size_t)g * QN + (size_t)gh * WC + gw) << 3));
        srcK[k] = s;
    }
    const int dstB = (tid & 448) << 4;

    auto stage_in = [&](int cc, int buf) {
        char* base = smem + buf * IBUF;
        #pragma unroll
        for (int k = 0; k < 7; ++k)
            gload16(srcK[k] + (cc << 20), base + (k << 13) + dstB);
    };
    auto stage_w = [&](int cc) {
        const char* wsrc = wtb + cc * 36864 + (tid << 4);
        #pragma unroll
        for (int k = 0; k < 4; ++k)
            gload16(wsrc + (k << 13), wB + (k << 13) + dstB);
        if (tid < 256)
            gload16(wsrc + (4 << 13), wB + (4 << 13) + dstB);
    };

    stage_in(0, 0);
    stage_w(0);
    __syncthreads();
    for (int cc = 0; cc < 4; ++cc) {
        if (cc < 3) stage_in(cc + 1, (cc + 1) & 1);   // hides under compute
        const char* bb = smem + (cc & 1) * IBUF;

        #pragma unroll
        for (int t = 0; t < 9; ++t) {
            const int kh = t / 3, kw = t % 3;
            f16x8 af[4], bf[4];
            #pragma unroll
            for (int m = 0; m < 4; ++m) {
                int co = m * 16 + l15;
                af[m] = *(const f16x8*)(wB + (t << 12) + (co << 6)
                                        + ((kg ^ ((co >> 1) & 3)) << 4));
            }
            #pragma unroll
            for (int n = 0; n < 4; ++n) {
                int wi = chf * 64 + (n << 4) + l15 + kw;
                int off = (lr + kh) * 8320 + wi * 64 + ((kg ^ ((wi >> 1) & 3)) << 4);
                bf[n] = *(const f16x8*)(bb + off);
            }
            #pragma unroll
            for (int m = 0; m < 4; ++m)
                #pragma unroll
                for (int n = 0; n < 4; ++n)
                    acc[m][n] = __builtin_amdgcn_mfma_f32_16x16x32_f16(af[m], bf[n], acc[m][n], 0, 0, 0);
        }
        __syncthreads();                      // drains input prefetch (hidden)
        if (cc < 3) {
            stage_w(cc + 1);                  // 36.9KB L2-hot refill
            __syncthreads();
        }
    }

    // ---- epilogue (granule-major stores/res) ----
    const int r4 = kg * 4;
    const int qb = lr * 128 + chf * 64;       // q within tile (+n*16+l15)
    if (GLU) {
        #pragma unroll
        for (int mv = 0; mv < 2; ++mv) {
            const int v0 = cb * 32 + mv * 16 + r4;
            float s1[4], o1[4], s2[4], o2[4];
            #pragma unroll
            for (int r = 0; r < 4; ++r) {
                s1[r] = gamma[v0 + r] * BN_SC;        o1[r] = beta[v0 + r];
                s2[r] = gamma[v0 + r + HALF] * BN_SC; o2[r] = beta[v0 + r + HALF];
            }
            #pragma unroll
            for (int n = 0; n < 4; ++n) {
                const int qc = qb + (n << 4) + l15;
                float ov[4];
                #pragma unroll
                for (int r = 0; r < 4; ++r) {
                    float yv = acc[mv][n][r] * s1[r] + o1[r];
                    float zv = acc[mv + 2][n][r] * s2[r] + o2[r];
                    ov[r] = yv / (1.0f + __expf(-zv));
                }
                f16x4 tv;
                #pragma unroll
                for (int r = 0; r < 4; ++r) tv[r] = (f16)ov[r];
                *(f16x4*)(outh + ((((size_t)b * (OCH / 8) + (v0 >> 3)) << 14)
                                  + q0 + qc) * 8 + (v0 & 7)) = tv;
            }
        }
    } else {
        #pragma unroll
        for (int m = 0; m < 4; ++m) {
            const int c0 = cb * 64 + m * 16 + r4;
            float s[4], o[4];
            #pragma unroll
            for (int r = 0; r < 4; ++r) {
                s[r] = gamma[c0 + r] * BN_SC; o[r] = beta[c0 + r];
            }
            #pragma unroll
            for (int n = 0; n < 4; ++n) {
                const int qc = qb + (n << 4) + l15;
                const size_t gaddr = ((((size_t)b * 16 + (c0 >> 3)) << 14) + q0 + qc) * 8 + (c0 & 7);
                float ov[4];
                #pragma unroll
                for (int r = 0; r < 4; ++r) ov[r] = acc[m][n][r] * s[r] + o[r];
                if (RES) {
                    f16x4 rv = *(const f16x4*)(res + gaddr);
                    #pragma unroll
                    for (int r = 0; r < 4; ++r) ov[r] += (float)rv[r];
                }
                f16x4 tv;
                #pragma unroll
                for (int r = 0; r < 4; ++r) tv[r] = (f16)ov[r];
                *(f16x4*)(outh + gaddr) = tv;
            }
        }
    }
}

// ---------------- UP conv (R9 version): 2-phase pipelined, dbuf LDS ---------
__global__ __launch_bounds__(512, 1) void conv_up_k(
        const f16* __restrict__ in, const f16* __restrict__ wt,
        const float* __restrict__ gamma, const float* __restrict__ beta,
        float* __restrict__ outf, const char* __restrict__ zeros) {
    constexpr int HIN = 128, WIN = 128;
    constexpr int BUFB = 24960 + 32768;       // input + weights per buffer
    __shared__ char smem[2 * BUFB];           // 115,456 B -> 1 block/CU

    const int tid = threadIdx.x, lane = tid & 63, wv = tid >> 6;
    const int l15 = lane & 15, kg = lane >> 4;
    const int b = blockIdx.z, cb = blockIdx.y;
    const int j = blockIdx.x >> 1, ph = blockIdx.x & 1;
    const int rr = wv >> 2;                   // output row within pair
    const int p  = (wv >> 1) & 1;             // output col parity
    const int jq = ((wv & 1) << 6) + l15;     // source col base (+n*16)

    f32x4 acc[4][4];
    #pragma unroll
    for (int m = 0; m < 4; ++m)
        #pragma unroll
        for (int n = 0; n < 4; ++n) acc[m][n] = (f32x4){0.f, 0.f, 0.f, 0.f};

    const f16* inb = in + (size_t)b * HIN * WIN * 128;
    const char* wtb = (const char*)wt + (size_t)(cb * 2 + ph) * 131072;

    // hoisted sources: 3 full iters (512 thr) + 24-granule tail (wave 0)
    const char* srcK[4];
    #pragma unroll
    for (int k = 0; k < 4; ++k) {
        int idx = (k < 3) ? ((k << 9) + tid) : (1536 + tid);
        int r = idx / 520;
        int rem = idx - r * 520;
        int wi = rem >> 2, gp = rem & 3;
        int g = gp ^ ((wi >> 1) & 3);
        int sh = 2 * j - 1 + ph + r;
        int sw = wi - 1;
        const char* s = zeros;
        if (r < 3 && (unsigned)sh < (unsigned)HIN && (unsigned)sw < (unsigned)WIN)
            s = (const char*)(inb + (((size_t)g * (HIN * WIN) + (size_t)sh * WIN + sw) << 3));
        srcK[k] = s;
    }
    const int dstB = (tid & 448) << 4;

    auto stage = [&](int cc, int buf) {
        char* base = smem + buf * BUFB;
        #pragma unroll
        for (int k = 0; k < 3; ++k)
            gload16(srcK[k] + (cc << 20), base + (k << 13) + dstB);
        if (tid < 24)
            gload16(srcK[3] + (cc << 20), base + 24576);
        const char* wsrc = wtb + cc * 32768 + (tid << 4);
        #pragma unroll
        for (int k = 0; k < 4; ++k)
            gload16(wsrc + (k << 13), base + 24960 + (k << 13) + dstB);
    };

    stage(0, 0);
    __syncthreads();                          // buf0 ready
    for (int cc = 0; cc < 4; ++cc) {
        if (cc < 3) stage(cc + 1, (cc + 1) & 1);   // issue BEFORE compute
        const char* bb = smem + (cc & 1) * BUFB;
        const char* wB = bb + 24960;

        #pragma unroll
        for (int t = 0; t < 4; ++t) {
            f16x8 af[4], bf[4];
            const int tapbase = (p * 4 + t) << 12;
            #pragma unroll
            for (int m = 0; m < 4; ++m) {
                int co = m * 16 + l15;
                af[m] = *(const f16x8*)(wB + tapbase + (co << 6)
                                        + ((kg ^ ((co >> 1) & 3)) << 4));
            }
            #pragma unroll
            for (int n = 0; n < 4; ++n) {
                int si = jq + (n << 4) + (t & 1) + p;       // halo'd source col
                int off = (rr + (t >> 1)) * 8320 + si * 64
                          + ((kg ^ ((si >> 1) & 3)) << 4);
                bf[n] = *(const f16x8*)(bb + off);
            }
            #pragma unroll
            for (int m = 0; m < 4; ++m)
                #pragma unroll
                for (int n = 0; n < 4; ++n)
                    acc[m][n] = __builtin_amdgcn_mfma_f32_16x16x32_f16(af[m], bf[n], acc[m][n], 0, 0, 0);
        }
        __syncthreads();                      // drains prefetch (hidden by MFMA)
    }

    // epilogue: BN + GLU -> fp32 NCHW
    const int r4 = kg * 4;
    const int h = 4 * j + 2 * rr + ph;
    #pragma unroll
    for (int mv = 0; mv < 2; ++mv) {
        const int v0 = cb * 32 + mv * 16 + r4;
        float s1[4], o1[4], s2[4], o2[4];
        #pragma unroll
        for (int r = 0; r < 4; ++r) {
            s1[r] = gamma[v0 + r] * BN_SC;      o1[r] = beta[v0 + r];
            s2[r] = gamma[v0 + r + 64] * BN_SC; o2[r] = beta[v0 + r + 64];
        }
        #pragma unroll
        for (int n = 0; n < 4; ++n) {
            const int w = 2 * (jq + (n << 4)) + p;
            float ov[4];
            #pragma unroll
            for (int r = 0; r < 4; ++r) {
                float yv = acc[mv][n][r] * s1[r] + o1[r];
                float zv = acc[mv + 2][n][r] * s2[r] + o2[r];
                ov[r] = yv / (1.0f + __expf(-zv));
            }
            #pragma unroll
            for (int r = 0; r < 4; ++r)
                outf[(((size_t)b * 64 + v0 + r) * 256 + h) * 256 + w] = ov[r];
        }
    }
}

// ---------------------------------------------------------------------------
extern "C" void kernel_launch(void* const* d_in, const int* in_sizes, int n_in,
                              void* d_out, int out_size, void* d_ws, size_t ws_size,
                              hipStream_t stream) {
    (void)in_sizes; (void)n_in; (void)out_size; (void)ws_size;
    const float* h_code    = (const float*)d_in[0];
    const float* word_embs = (const float*)d_in[2];
    const void*  mask      = d_in[3];
    const float* w_ctx     = (const float*)d_in[4];
    const float* r0_w1 = (const float*)d_in[5];
    const float* r0_g1 = (const float*)d_in[6];
    const float* r0_b1 = (const float*)d_in[7];
    const float* r0_w2 = (const float*)d_in[8];
    const float* r0_g2 = (const float*)d_in[9];
    const float* r0_b2 = (const float*)d_in[10];
    const float* r1_w1 = (const float*)d_in[11];
    const float* r1_g1 = (const float*)d_in[12];
    const float* r1_b1 = (const float*)d_in[13];
    const float* r1_w2 = (const float*)d_in[14];
    const float* r1_g2 = (const float*)d_in[15];
    const float* r1_b2 = (const float*)d_in[16];
    const float* up_w  = (const float*)d_in[17];
    const float* up_g  = (const float*)d_in[18];
    const float* up_b  = (const float*)d_in[19];

    float* outp = (float*)d_out;                         // (8,64,256,256) fp32
    float* attp = outp + (size_t)B_N * NGF * 4 * HC * WC;

    unsigned* mbits = (unsigned*)d_ws;
    float* sT  = (float*)((char*)d_ws + 1024);
    char* zeros = (char*)d_ws + ((size_t)4 << 20);                 // 3MB+64B span
    f16* hcA   = (f16*)((char*)d_ws + ((size_t)8 << 20));          // 32MB
    f16* wtbuf = (f16*)((char*)d_ws + ((size_t)40 << 20));         // ~3MB

    const int W1_TOT = 4 * 4 * 9 * 64 * 32;   // 294912 (GLU 256-out)
    const int W2_TOT = 2 * 4 * 9 * 64 * 32;   // 147456
    const int WUP_TOT = 2 * 2 * 4 * 2 * 4 * 64 * 32;   // 524288 (parity 2x2)
    f16* Wr0c1 = wtbuf;
    f16* Wr0c2 = Wr0c1 + W1_TOT;
    f16* Wr1c1 = Wr0c2 + W2_TOT;
    f16* Wr1c2 = Wr1c1 + W1_TOT;
    f16* Wup   = Wr1c2 + W2_TOT;

    f16* Bbuf = (f16*)d_out;                               // [0,32MB)
    f16* Cbuf = (f16*)((char*)d_out + ((size_t)32 << 20)); // [32,64MB)

    prep_mask_k<<<1, 64, 0, stream>>>(mask, mbits, (unsigned*)zeros);
    source_t_k<<<64, 256, 0, stream>>>(w_ctx, word_embs, sT);

    wt_transform_k<<<(W1_TOT + 255) / 256, 256, 0, stream>>>(r0_w1, Wr0c1, W1_TOT, 128);
    wt_transform_k<<<(W2_TOT + 255) / 256, 256, 0, stream>>>(r0_w2, Wr0c2, W2_TOT, 0);
    wt_transform_k<<<(W1_TOT + 255) / 256, 256, 0, stream>>>(r1_w1, Wr1c1, W1_TOT, 128);
    wt_transform_k<<<(W2_TOT + 255) / 256, 256, 0, stream>>>(r1_w2, Wr1c2, W2_TOT, 0);
    wt_up_transform_k<<<WUP_TOT / 256, 256, 0, stream>>>(up_w, Wup);

    attention_k<<<(B_N * QN) / 256, 256, 0, stream>>>(h_code, sT, mbits, attp, hcA);

    // r0: conv1+GLU (hcA->B), conv2+res hcA (B->C)
    conv_mfma_k<256, true,  false>
        <<<dim3(32, 4, B_N), 512, 0, stream>>>(hcA, Wr0c1, r0_g1, r0_b1, nullptr, Bbuf, zeros);
    conv_mfma_k<128, false, true>
        <<<dim3(32, 2, B_N), 512, 0, stream>>>(Bbuf, Wr0c2, r0_g2, r0_b2, hcA, Cbuf, zeros);
    // r1: conv1+GLU (C->B), conv2+res C (B->hcA)
    conv_mfma_k<256, true,  false>
        <<<dim3(32, 4, B_N), 512, 0, stream>>>(Cbuf, Wr1c1, r1_g1, r1_b1, nullptr, Bbuf, zeros);
    conv_mfma_k<128, false, true>
        <<<dim3(32, 2, B_N), 512, 0, stream>>>(Bbuf, Wr1c2, r1_g2, r1_b2, Cbuf, hcA, zeros);
    // upsample2x + conv + GLU -> final fp32 NCHW (R9 2-phase pipelined)
    conv_up_k<<<dim3(128, 2, B_N), 512, 0, stream>>>(hcA, Wup, up_g, up_b, outp, zeros);
}